// Round 5
// baseline (2125.346 us; speedup 1.0000x reference)
//
#include <hip/hip_runtime.h>

#define BB 4096
#define DD 512
#define NCC 5994
#define NSL 12                     // slices per row-block (divides 24 tiles)
#define XRB 32                     // 4096/128
#define CRB 47                     // ceil(5994/128)
#define NBLK ((XRB + CRB) * NSL)   // 948
#define PSZ (NSL * (BB + NCC))     // 121080

typedef __attribute__((ext_vector_type(8))) short bfx8;
typedef __attribute__((ext_vector_type(8))) unsigned short usx8;
typedef __attribute__((ext_vector_type(4))) float fx4;

__device__ __forceinline__ unsigned short f2bf(float f) {
    unsigned u = __builtin_bit_cast(unsigned, f);
    u += 0x7fff + ((u >> 16) & 1);   // RNE
    return (unsigned short)(u >> 16);
}

__device__ __forceinline__ void gload_lds16(const void* g, void* l) {
    __builtin_amdgcn_global_load_lds(
        (const __attribute__((address_space(1))) void*)g,
        (__attribute__((address_space(3))) void*)l, 16, 0, 0);
}

// ---------------------------------------------------------------------------
// Stage 1a: partial count/rank per sample (j-chunked, 8x parallel) + label_add.
// ---------------------------------------------------------------------------
__global__ void ranks_partial(const int* __restrict__ label, int* __restrict__ cnti,
                              int* __restrict__ ranki, float* __restrict__ label_add) {
    __shared__ int lab[512];
    int ib = blockIdx.x >> 3, jc = blockIdx.x & 7;
    int t = threadIdx.x;
    lab[t]       = label[jc * 512 + t];
    lab[t + 256] = label[jc * 512 + t + 256];
    __syncthreads();
    int i = ib * 256 + t;
    int li = label[i];
    int j0 = jc * 512;
    int cnt = 0, rk = 0;
    for (int j = 0; j < 512; ++j) {
        int e = (lab[j] == li) ? 1 : 0;
        cnt += e;
        rk += (j0 + j < i) ? e : 0;
    }
    atomicAdd(&cnti[i], cnt);
    atomicAdd(&ranki[i], rk);
    if (jc == 0) label_add[li] = 1.0f;
}

// ---------------------------------------------------------------------------
// Stage 1b: weighted scatter-add into cadd (zeroed by memset).
// w_i computed from (cnt, rank): first occ: 2^-(k-1); else 2^-(k-rank).
// ---------------------------------------------------------------------------
__global__ void cadd_kernel(const float* __restrict__ x, const int* __restrict__ label,
                            const int* __restrict__ cnti, const int* __restrict__ ranki,
                            float* __restrict__ cadd) {
    int i = blockIdx.x;
    int li = label[i];
    int cnt = cnti[i], rk = ranki[i];
    float expo = (rk == 0) ? (float)(cnt - 1) : (float)(cnt - rk);
    float wi = exp2f(-expo);
    const float* xr = x + (size_t)i * DD;
    float* cr = cadd + (size_t)li * DD;
    int t = threadIdx.x;
    atomicAdd(&cr[t], wi * xr[t]);
    atomicAdd(&cr[t + 256], wi * xr[t + 256]);
}

// ---------------------------------------------------------------------------
// Stage 2: alpha = sigmoid(centers @ fc_w + fc_b); blend; write bf16 ncb.
// ---------------------------------------------------------------------------
__global__ void newcenter_kernel(const float* __restrict__ centers,
                                 const float* __restrict__ fc_w,
                                 const float* __restrict__ fc_b,
                                 const float* __restrict__ cadd,
                                 const float* __restrict__ label_add,
                                 unsigned short* __restrict__ ncb) {
    int l = blockIdx.x;
    int t = threadIdx.x;
    const float* cr = centers + (size_t)l * DD;
    float part = fmaf(cr[t], fc_w[t], cr[t + 256] * fc_w[t + 256]);
#pragma unroll
    for (int off = 32; off; off >>= 1) part += __shfl_xor(part, off);
    __shared__ float wsum[4];
    if ((t & 63) == 0) wsum[t >> 6] = part;
    __syncthreads();
    float dot = wsum[0] + wsum[1] + wsum[2] + wsum[3] + fc_b[0];
    float alpha = 1.0f / (1.0f + expf(-dot));
    float la = label_add[l];
    float gate = alpha * la + (1.0f - la);
    float beta = (1.0f - alpha) * la;
    const float* car = cadd + (size_t)l * DD;
    unsigned short* nr = ncb + (size_t)l * DD;
    nr[t]       = f2bf(fmaf(cr[t],       gate, car[t]       * beta));
    nr[t + 256] = f2bf(fmaf(cr[t + 256], gate, car[t + 256] * beta));
}

// ---------------------------------------------------------------------------
// fp32 -> bf16 bulk convert (x and ch_w).
// ---------------------------------------------------------------------------
__global__ void conv_kernel(const float* __restrict__ src, unsigned short* __restrict__ dst,
                            int n) {
    int i = blockIdx.x * 256 + threadIdx.x;
    if (i * 8 >= n) return;
    const float4* g = (const float4*)(src + (size_t)i * 8);
    float4 v0 = g[0], v1 = g[1];
    usx8 u;
    u[0] = f2bf(v0.x); u[1] = f2bf(v0.y); u[2] = f2bf(v0.z); u[3] = f2bf(v0.w);
    u[4] = f2bf(v1.x); u[5] = f2bf(v1.y); u[6] = f2bf(v1.z); u[7] = f2bf(v1.w);
    *(usx8*)(dst + (size_t)i * 8) = u;
}

// ---------------------------------------------------------------------------
// Fused MFMA GEMM + online softmax/CE partials.
// Block: 128 rows x 256 cols per tile, 2 tiles per slice, K=512 in k32 chunks.
// 8 waves (2 wm x 4 wn), wave tile 64x64 (4x4 16x16x32 frags).
// A chunk 8KB + B chunk 16KB, double-buffered = 48 KB LDS -> 3 blocks/CU.
// Staging via global_load_lds w/ source-side 4-slot XOR swizzle (linear dest);
// reads use the same XOR -> conflict-free ds_read_b128.
// ---------------------------------------------------------------------------
__global__ __launch_bounds__(512, 6) void mfma_ce_kernel(
    const unsigned short* __restrict__ xb, const unsigned short* __restrict__ ncb,
    const unsigned short* __restrict__ wb, const float* __restrict__ chb,
    const int* __restrict__ labelg,
    float* __restrict__ pm, float* __restrict__ ps, float* __restrict__ pt,
    float* __restrict__ pv, int* __restrict__ pi)
{
    __shared__ short lA[2][128 * 32];   // 8 KB each
    __shared__ short lB[2][256 * 32];   // 16 KB each

    int b = blockIdx.x;
    int xm, rb, slice, nrows;
    const unsigned short* src;
    if (b < XRB * NSL) { xm = 1; rb = b % XRB; slice = b / XRB; nrows = BB;  src = xb; }
    else { int c = b - XRB * NSL; xm = 0; rb = c % CRB; slice = c / CRB; nrows = NCC; src = ncb; }
    int row0  = rb * 128;
    int tile0 = slice * 2;

    int t = threadIdx.x, lane = t & 63, wv = t >> 6;
    int wm = wv >> 2, wn = wv & 3;
    int l15 = lane & 15, l4 = lane >> 4;

    // ---- staging addresses (source-side swizzle, linear LDS dest) ----
    // LDS slot s of row/col r holds source k8 = s ^ ((r>>1)&3); here dest slot
    // = lane&3 and (rloc>>1)&3 = (lane>>3)&3, so sk8 is lane-only.
    int sk8 = (lane & 3) ^ ((lane >> 3) & 3);
    int arow = min(row0 + wv * 16 + (lane >> 2), nrows - 1);
    const unsigned short* aSrc = src + (size_t)arow * DD + sk8 * 8;
    int bcol_loc = wv * 32 + (lane >> 2);

    // ---- fragment read offsets (bytes) ----
    int slot = (l4 ^ ((l15 >> 1) & 3)) << 4;
    int aoff = wm * 4096 + l15 * 64 + slot;          // + mf*1024
    int boff = (wn * 64 + l15) * 64 + slot;          // + nf*1024

    // ---- softmax state: row = row0 + wm*64 + mf*16 + l4*4 + j ----
    float m_[4][4], s_[4][4], tg_[4][4], av_[4][4];
    int ai_[4][4], tc_[4][4];
#pragma unroll
    for (int mf = 0; mf < 4; ++mf)
#pragma unroll
        for (int j = 0; j < 4; ++j) {
            m_[mf][j] = -1e30f; s_[mf][j] = 0.f; tg_[mf][j] = 0.f;
            av_[mf][j] = -1e30f; ai_[mf][j] = 0x7fffffff;
            int grow = row0 + wm * 64 + mf * 16 + l4 * 4 + j;
            tc_[mf][j] = xm ? labelg[grow] : grow;
        }

    auto stage = [&](int s, int bufIdx) {
        int tt = tile0 + (s >> 4);
        int kc = s & 15;
        gload_lds16(aSrc + kc * 32, &lA[bufIdx][wv * 512]);
        int colbase = tt * 256 + bcol_loc;
        const unsigned short* bs0 = wb + (size_t)min(colbase,      NCC - 1) * DD + kc * 32 + sk8 * 8;
        const unsigned short* bs1 = wb + (size_t)min(colbase + 16, NCC - 1) * DD + kc * 32 + sk8 * 8;
        short* bd = &lB[bufIdx][wv * 1024];
        gload_lds16(bs0, bd);
        gload_lds16(bs1, bd + 512);
    };

    stage(0, 0);
    __syncthreads();

    fx4 acc[4][4];
    float biasv[4];
    int buf = 0;

    for (int s = 0; s < 32; ++s) {
        int kc = s & 15;
        int tt = tile0 + (s >> 4);
        if (s + 1 < 32) stage(s + 1, buf ^ 1);
        if (kc == 0) {
#pragma unroll
            for (int mf = 0; mf < 4; ++mf)
#pragma unroll
                for (int nf = 0; nf < 4; ++nf) {
                    fx4 z = {0.f, 0.f, 0.f, 0.f};
                    acc[mf][nf] = z;
                }
#pragma unroll
            for (int nf = 0; nf < 4; ++nf) {
                int col = tt * 256 + wn * 64 + nf * 16 + l15;
                biasv[nf] = (col < NCC) ? chb[col] : 0.f;
            }
        }
        const char* Ab = (const char*)lA[buf];
        const char* Bb = (const char*)lB[buf];
        bfx8 a0 = *(const bfx8*)(Ab + aoff);
        bfx8 a1 = *(const bfx8*)(Ab + aoff + 1024);
        bfx8 a2 = *(const bfx8*)(Ab + aoff + 2048);
        bfx8 a3 = *(const bfx8*)(Ab + aoff + 3072);
        bfx8 b0 = *(const bfx8*)(Bb + boff);
        bfx8 b1 = *(const bfx8*)(Bb + boff + 1024);
        bfx8 b2 = *(const bfx8*)(Bb + boff + 2048);
        bfx8 b3 = *(const bfx8*)(Bb + boff + 3072);
        acc[0][0] = __builtin_amdgcn_mfma_f32_16x16x32_bf16(a0, b0, acc[0][0], 0, 0, 0);
        acc[0][1] = __builtin_amdgcn_mfma_f32_16x16x32_bf16(a0, b1, acc[0][1], 0, 0, 0);
        acc[0][2] = __builtin_amdgcn_mfma_f32_16x16x32_bf16(a0, b2, acc[0][2], 0, 0, 0);
        acc[0][3] = __builtin_amdgcn_mfma_f32_16x16x32_bf16(a0, b3, acc[0][3], 0, 0, 0);
        acc[1][0] = __builtin_amdgcn_mfma_f32_16x16x32_bf16(a1, b0, acc[1][0], 0, 0, 0);
        acc[1][1] = __builtin_amdgcn_mfma_f32_16x16x32_bf16(a1, b1, acc[1][1], 0, 0, 0);
        acc[1][2] = __builtin_amdgcn_mfma_f32_16x16x32_bf16(a1, b2, acc[1][2], 0, 0, 0);
        acc[1][3] = __builtin_amdgcn_mfma_f32_16x16x32_bf16(a1, b3, acc[1][3], 0, 0, 0);
        acc[2][0] = __builtin_amdgcn_mfma_f32_16x16x32_bf16(a2, b0, acc[2][0], 0, 0, 0);
        acc[2][1] = __builtin_amdgcn_mfma_f32_16x16x32_bf16(a2, b1, acc[2][1], 0, 0, 0);
        acc[2][2] = __builtin_amdgcn_mfma_f32_16x16x32_bf16(a2, b2, acc[2][2], 0, 0, 0);
        acc[2][3] = __builtin_amdgcn_mfma_f32_16x16x32_bf16(a2, b3, acc[2][3], 0, 0, 0);
        acc[3][0] = __builtin_amdgcn_mfma_f32_16x16x32_bf16(a3, b0, acc[3][0], 0, 0, 0);
        acc[3][1] = __builtin_amdgcn_mfma_f32_16x16x32_bf16(a3, b1, acc[3][1], 0, 0, 0);
        acc[3][2] = __builtin_amdgcn_mfma_f32_16x16x32_bf16(a3, b2, acc[3][2], 0, 0, 0);
        acc[3][3] = __builtin_amdgcn_mfma_f32_16x16x32_bf16(a3, b3, acc[3][3], 0, 0, 0);

        if (kc == 15) {
#pragma unroll
            for (int nf = 0; nf < 4; ++nf) {
                int col = tt * 256 + wn * 64 + nf * 16 + l15;
                bool cv = col < NCC;
#pragma unroll
                for (int mf = 0; mf < 4; ++mf)
#pragma unroll
                    for (int j = 0; j < 4; ++j) {
                        if (cv) {
                            float v = acc[mf][nf][j] + biasv[nf];
                            float nm = fmaxf(m_[mf][j], v);
                            s_[mf][j] = s_[mf][j] * __expf(m_[mf][j] - nm) + __expf(v - nm);
                            m_[mf][j] = nm;
                            if (xm && v > av_[mf][j]) { av_[mf][j] = v; ai_[mf][j] = col; }
                            if (col == tc_[mf][j]) tg_[mf][j] = v;
                        }
                    }
            }
        }
        __syncthreads();
        buf ^= 1;
    }

    // intra-wave merge across the 16-lane col group
#pragma unroll
    for (int off = 1; off < 16; off <<= 1) {
#pragma unroll
        for (int mf = 0; mf < 4; ++mf)
#pragma unroll
            for (int j = 0; j < 4; ++j) {
                float om = __shfl_xor(m_[mf][j], off);
                float os = __shfl_xor(s_[mf][j], off);
                float ot = __shfl_xor(tg_[mf][j], off);
                float ov = __shfl_xor(av_[mf][j], off);
                int   oi = __shfl_xor(ai_[mf][j], off);
                float nm = fmaxf(m_[mf][j], om);
                s_[mf][j] = s_[mf][j] * __expf(m_[mf][j] - nm) + os * __expf(om - nm);
                m_[mf][j] = nm;
                tg_[mf][j] += ot;
                if (ov > av_[mf][j] || (ov == av_[mf][j] && oi < ai_[mf][j])) {
                    av_[mf][j] = ov; ai_[mf][j] = oi;
                }
            }
    }

    // cross-wave merge (4 wn-waves) via LDS (reuse lB after final barrier)
    float* red = (float*)lB;          // [4 arrays][4 wn][128 rows] + int array
    int* redi = (int*)(red + 4 * 512);
    if (l15 == 0) {
#pragma unroll
        for (int mf = 0; mf < 4; ++mf)
#pragma unroll
            for (int j = 0; j < 4; ++j) {
                int rowloc = wm * 64 + mf * 16 + l4 * 4 + j;
                int idx = wn * 128 + rowloc;
                red[0 * 512 + idx] = m_[mf][j];
                red[1 * 512 + idx] = s_[mf][j];
                red[2 * 512 + idx] = tg_[mf][j];
                red[3 * 512 + idx] = av_[mf][j];
                redi[idx]          = ai_[mf][j];
            }
    }
    __syncthreads();
    if (t < 128) {
        int grow = row0 + t;
        if (grow < nrows) {
            float M = -1e30f, S = 0.f, T = 0.f, V = -1e30f; int I = 0x7fffffff;
#pragma unroll
            for (int wn2 = 0; wn2 < 4; ++wn2) {
                int idx = wn2 * 128 + t;
                float m2 = red[idx], s2 = red[512 + idx];
                float nm = fmaxf(M, m2);
                S = S * __expf(M - nm) + s2 * __expf(m2 - nm); M = nm;
                T += red[1024 + idx];
                float v2 = red[1536 + idx]; int i2 = redi[idx];
                if (v2 > V || (v2 == V && i2 < I)) { V = v2; I = i2; }
            }
            int pidx = xm ? (grow * NSL + slice) : (BB * NSL + grow * NSL + slice);
            pm[pidx] = M; ps[pidx] = S; pt[pidx] = T; pv[pidx] = V; pi[pidx] = I;
        }
    }
}

// ---------------------------------------------------------------------------
// Merge partials per row -> CE / prec1 accumulators.
// ---------------------------------------------------------------------------
__global__ void merge_kernel(const float* __restrict__ pm, const float* __restrict__ ps,
                             const float* __restrict__ pt, const float* __restrict__ pv,
                             const int* __restrict__ pi, const int* __restrict__ label,
                             float* __restrict__ sums) {
    int tid = blockIdx.x * 256 + threadIdx.x;
    float ce = 0.f, corr = 0.f;
    int isx = (tid < BB) ? 1 : 0;
    int base = -1;
    if (tid < BB) base = tid * NSL;
    else if (tid < BB + NCC) base = BB * NSL + (tid - BB) * NSL;
    if (base >= 0) {
        float M = -1e30f, S = 0.f, T = 0.f, V = -1e30f; int I = 0x7fffffff;
#pragma unroll
        for (int s2 = 0; s2 < NSL; ++s2) {
            float m = pm[base + s2], s = ps[base + s2];
            float nm = fmaxf(M, m);
            S = S * __expf(M - nm) + s * __expf(m - nm); M = nm;
            T += pt[base + s2];
            float v = pv[base + s2]; int i2 = pi[base + s2];
            if (v > V || (v == V && i2 < I)) { V = v; I = i2; }
        }
        ce = -(T - M - logf(S));
        if (isx) corr = (I == label[tid]) ? 1.f : 0.f;
    }
#pragma unroll
    for (int off = 32; off; off >>= 1) {
        ce += __shfl_xor(ce, off);
        corr += __shfl_xor(corr, off);
    }
    if ((threadIdx.x & 63) == 0) {
        atomicAdd(&sums[isx ? 0 : 2], ce);
        if (isx) atomicAdd(&sums[1], corr);
    }
}

__global__ void finalize_kernel(const float* __restrict__ sums, float* __restrict__ out) {
    out[0] = sums[0] / (float)BB + sums[2] / (float)NCC;
    out[1] = 100.0f * sums[1] / (float)BB;
}

extern "C" void kernel_launch(void* const* d_in, const int* in_sizes, int n_in,
                              void* d_out, int out_size, void* d_ws, size_t ws_size,
                              hipStream_t stream) {
    const float* x       = (const float*)d_in[0];
    const int*   label   = (const int*)d_in[1];
    const float* centers = (const float*)d_in[2];
    const float* fc_w    = (const float*)d_in[3];
    const float* fc_b    = (const float*)d_in[4];
    const float* ch_w    = (const float*)d_in[5];
    const float* ch_b    = (const float*)d_in[6];
    float* out = (float*)d_out;

    // ws layout (float offsets):
    // 0: cnti[4096] | 4096: ranki[4096] | 8192: label_add[5994] | 14186: sums[6]
    // 14192: cadd[3069952]  -- consumed by newcenter, then REUSED:
    //        14192: partials pm/ps/pt/pv/pi (5*121080=605400)
    //        619592: wb bf16 ch_w (1534464 float-slots)
    // 3084144: xb bf16 x (1048576) | 4132720: ncb bf16 new_center (1534464)
    // total 5667184 floats = 22.7 MB
    float* ws = (float*)d_ws;
    int*   cnti      = (int*)ws;
    int*   ranki     = cnti + BB;
    float* label_add = ws + 2 * BB;
    float* sums      = ws + 14186;
    float* cadd      = ws + 14192;
    float* pm        = ws + 14192;
    float* ps        = pm + PSZ;
    float* pt        = ps + PSZ;
    float* pv        = pt + PSZ;
    int*   pi        = (int*)(pv + PSZ);
    unsigned short* wbuf  = (unsigned short*)(ws + 619592);
    unsigned short* xbuf  = (unsigned short*)(ws + 3084144);
    unsigned short* ncbuf = (unsigned short*)(ws + 4132720);

    hipMemsetAsync(ws, 0, 14192 * sizeof(float), stream);                 // cnti/ranki/label_add/sums
    hipMemsetAsync(cadd, 0, (size_t)NCC * DD * sizeof(float), stream);    // cadd

    ranks_partial<<<128, 256, 0, stream>>>(label, cnti, ranki, label_add);
    cadd_kernel<<<BB, 256, 0, stream>>>(x, label, cnti, ranki, cadd);
    newcenter_kernel<<<NCC, 256, 0, stream>>>(centers, fc_w, fc_b, cadd, label_add, ncbuf);
    // cadd consumed; overlay region now safe for wb + partials
    conv_kernel<<<(NCC * DD / 8 + 255) / 256, 256, 0, stream>>>(ch_w, wbuf, NCC * DD);
    conv_kernel<<<(BB * DD / 8 + 255) / 256, 256, 0, stream>>>(x, xbuf, BB * DD);

    mfma_ce_kernel<<<NBLK, 512, 0, stream>>>(xbuf, ncbuf, wbuf, ch_b, label,
                                             pm, ps, pt, pv, pi);

    merge_kernel<<<(BB + NCC + 255) / 256, 256, 0, stream>>>(pm, ps, pt, pv, pi, label, sums);
    finalize_kernel<<<1, 1, 0, stream>>>(sums, out);
}

// Round 7
// 286.735 us; speedup vs baseline: 7.4122x; 7.4122x over previous
//
#include <hip/hip_runtime.h>

#define BB 4096
#define DD 512
#define NCC 5994
#define RBX 64                      // x row-blocks (4096/64)
#define RBC 94                      // nc row-blocks (6016/64)
#define NSL 12                      // col-slices; each = 4 tiles of 128 cols
#define TPS 4
#define NBLK ((RBX + RBC) * NSL)    // 1896
#define PSZ (NSL * (BB + NCC))      // 121080

typedef __attribute__((ext_vector_type(8))) short bfx8;
typedef __attribute__((ext_vector_type(8))) unsigned short usx8;
typedef __attribute__((ext_vector_type(4))) float fx4;

__device__ __forceinline__ unsigned short f2bf(float f) {
    unsigned u = __builtin_bit_cast(unsigned, f);
    u += 0x7fff + ((u >> 16) & 1);   // RNE
    return (unsigned short)(u >> 16);
}

__device__ __forceinline__ void gload_lds16(const void* g, void* l) {
    __builtin_amdgcn_global_load_lds(
        (const __attribute__((address_space(1))) void*)g,
        (__attribute__((address_space(3))) void*)l, 16, 0, 0);
}

// ---------------------------------------------------------------------------
// Stage 1a: partial count/rank per sample (j-chunked, 8x parallel) + label_add.
// ---------------------------------------------------------------------------
__global__ void ranks_partial(const int* __restrict__ label, int* __restrict__ cnti,
                              int* __restrict__ ranki, float* __restrict__ label_add) {
    __shared__ int lab[512];
    int ib = blockIdx.x >> 3, jc = blockIdx.x & 7;
    int t = threadIdx.x;
    lab[t]       = label[jc * 512 + t];
    lab[t + 256] = label[jc * 512 + t + 256];
    __syncthreads();
    int i = ib * 256 + t;
    int li = label[i];
    int j0 = jc * 512;
    int cnt = 0, rk = 0;
    for (int j = 0; j < 512; ++j) {
        int e = (lab[j] == li) ? 1 : 0;
        cnt += e;
        rk += (j0 + j < i) ? e : 0;
    }
    atomicAdd(&cnti[i], cnt);
    atomicAdd(&ranki[i], rk);
    if (jc == 0) label_add[li] = 1.0f;
}

// ---------------------------------------------------------------------------
// Stage 1b: weighted scatter-add into cadd (zeroed by memset).
// ---------------------------------------------------------------------------
__global__ void cadd_kernel(const float* __restrict__ x, const int* __restrict__ label,
                            const int* __restrict__ cnti, const int* __restrict__ ranki,
                            float* __restrict__ cadd) {
    int i = blockIdx.x;
    int li = label[i];
    int cnt = cnti[i], rk = ranki[i];
    float expo = (rk == 0) ? (float)(cnt - 1) : (float)(cnt - rk);
    float wi = exp2f(-expo);
    const float* xr = x + (size_t)i * DD;
    float* cr = cadd + (size_t)li * DD;
    int t = threadIdx.x;
    atomicAdd(&cr[t], wi * xr[t]);
    atomicAdd(&cr[t + 256], wi * xr[t + 256]);
}

// ---------------------------------------------------------------------------
// Stage 2: alpha = sigmoid(centers @ fc_w + fc_b); blend; write bf16 ncb.
// ---------------------------------------------------------------------------
__global__ void newcenter_kernel(const float* __restrict__ centers,
                                 const float* __restrict__ fc_w,
                                 const float* __restrict__ fc_b,
                                 const float* __restrict__ cadd,
                                 const float* __restrict__ label_add,
                                 unsigned short* __restrict__ ncb) {
    int l = blockIdx.x;
    int t = threadIdx.x;
    const float* cr = centers + (size_t)l * DD;
    float part = fmaf(cr[t], fc_w[t], cr[t + 256] * fc_w[t + 256]);
#pragma unroll
    for (int off = 32; off; off >>= 1) part += __shfl_xor(part, off);
    __shared__ float wsum[4];
    if ((t & 63) == 0) wsum[t >> 6] = part;
    __syncthreads();
    float dot = wsum[0] + wsum[1] + wsum[2] + wsum[3] + fc_b[0];
    float alpha = 1.0f / (1.0f + expf(-dot));
    float la = label_add[l];
    float gate = alpha * la + (1.0f - la);
    float beta = (1.0f - alpha) * la;
    const float* car = cadd + (size_t)l * DD;
    unsigned short* nr = ncb + (size_t)l * DD;
    nr[t]       = f2bf(fmaf(cr[t],       gate, car[t]       * beta));
    nr[t + 256] = f2bf(fmaf(cr[t + 256], gate, car[t + 256] * beta));
}

// ---------------------------------------------------------------------------
// fp32 -> bf16 bulk convert: x (first BB*DD/8 chunks) then ch_w.
// ---------------------------------------------------------------------------
__global__ void conv_both(const float* __restrict__ xs, const float* __restrict__ wsrc,
                          unsigned short* __restrict__ xd, unsigned short* __restrict__ wd) {
    int i = blockIdx.x * 256 + threadIdx.x;
    const float* src;
    unsigned short* dst;
    if (i < BB * DD / 8) { src = xs; dst = xd; }
    else {
        i -= BB * DD / 8;
        if (i >= NCC * DD / 8) return;
        src = wsrc; dst = wd;
    }
    const float4* g = (const float4*)(src + (size_t)i * 8);
    float4 v0 = g[0], v1 = g[1];
    usx8 u;
    u[0] = f2bf(v0.x); u[1] = f2bf(v0.y); u[2] = f2bf(v0.z); u[3] = f2bf(v0.w);
    u[4] = f2bf(v1.x); u[5] = f2bf(v1.y); u[6] = f2bf(v1.z); u[7] = f2bf(v1.w);
    *(usx8*)(dst + (size_t)i * 8) = u;
}

// ---------------------------------------------------------------------------
// Fused MFMA GEMM + online softmax/CE partials.
// 256 threads = 4 waves (2 wm x 2 wn), wave tile 32x64 -> block 64 rows x 128
// cols per tile, TPS=4 tiles per block, K=512 in k32 double-buffered chunks.
// LDS 24 KB; __launch_bounds__(256,4): VGPR<=128, 4 blocks/CU.
// ---------------------------------------------------------------------------
__global__ __launch_bounds__(256, 4) void mfma_ce_kernel(
    const unsigned short* __restrict__ xb, const unsigned short* __restrict__ ncb,
    const unsigned short* __restrict__ wb, const float* __restrict__ chb,
    const int* __restrict__ labelg,
    float* __restrict__ pm, float* __restrict__ ps, float* __restrict__ pt,
    float* __restrict__ pv, int* __restrict__ pi)
{
    __shared__ short lA[2][64 * 32];    // 4 KB each
    __shared__ short lB[2][128 * 32];   // 8 KB each

    int b = blockIdx.x;
    int xm, rb, slice, nrows;
    const unsigned short* src;
    if (b < RBX * NSL) { xm = 1; rb = b % RBX; slice = b / RBX; nrows = BB;  src = xb; }
    else { int c = b - RBX * NSL; xm = 0; rb = c % RBC; slice = c / RBC; nrows = NCC; src = ncb; }
    int row0  = rb * 64;
    int tile0 = slice * TPS;

    int t = threadIdx.x, lane = t & 63, wv = t >> 6;
    int wm = wv >> 1, wn = wv & 1;
    int l15 = lane & 15, l4 = lane >> 4;

    // staging: dest linear (wave base + lane*16); source k8-group pre-swizzled
    int sk8  = (lane & 3) ^ ((lane >> 3) & 3);
    int rloc = t >> 2;                                   // 0..63
    const unsigned short* aSrcB =
        src + (size_t)min(row0 + rloc, nrows - 1) * DD + sk8 * 8;

    // fragment read offsets (bytes), same XOR on the read side
    int slot = (l4 ^ ((l15 >> 1) & 3)) << 4;
    int aoff = (wm * 32 + l15) * 64 + slot;              // + mf*1024
    int boff = (wn * 64 + l15) * 64 + slot;              // + nf*1024

    // softmax state: row = row0 + wm*32 + mf*16 + l4*4 + j
    float m_[2][4], s_[2][4], tg_[2][4], av_[2][4];
    int ai_[2][4], tc_[2][4];
#pragma unroll
    for (int mf = 0; mf < 2; ++mf)
#pragma unroll
        for (int j = 0; j < 4; ++j) {
            m_[mf][j] = -1e30f; s_[mf][j] = 0.f; tg_[mf][j] = 0.f;
            av_[mf][j] = -1e30f; ai_[mf][j] = 0x7fffffff;
            int grow = row0 + wm * 32 + mf * 16 + l4 * 4 + j;
            tc_[mf][j] = xm ? labelg[min(grow, BB - 1)] : grow;
        }

    auto stage = [&](int s, int bufIdx) {
        int tile = tile0 + (s >> 4);
        int ko = (s & 15) * 32 + sk8 * 8;                // k-offset incl. swizzle
        gload_lds16(aSrcB + (s & 15) * 32, &lA[bufIdx][wv * 512]);
        int c0 = tile * 128 + rloc;
        const unsigned short* b0 = wb + (size_t)min(c0,      NCC - 1) * DD + ko;
        const unsigned short* b1 = wb + (size_t)min(c0 + 64, NCC - 1) * DD + ko;
        gload_lds16(b0, &lB[bufIdx][wv * 512]);
        gload_lds16(b1, &lB[bufIdx][2048 + wv * 512]);
    };

    stage(0, 0);
    __syncthreads();

    fx4 acc[2][4];
    float biasv[4];
    int buf = 0;

    for (int s = 0; s < TPS * 16; ++s) {
        int kc = s & 15;
        int tile = tile0 + (s >> 4);
        if (s + 1 < TPS * 16) stage(s + 1, buf ^ 1);
        if (kc == 0) {
#pragma unroll
            for (int mf = 0; mf < 2; ++mf)
#pragma unroll
                for (int nf = 0; nf < 4; ++nf) {
                    fx4 z = {0.f, 0.f, 0.f, 0.f};
                    acc[mf][nf] = z;
                }
#pragma unroll
            for (int nf = 0; nf < 4; ++nf) {
                int col = tile * 128 + wn * 64 + nf * 16 + l15;
                biasv[nf] = (col < NCC) ? chb[col] : 0.f;
            }
        }
        const char* Ab = (const char*)lA[buf];
        const char* Bb = (const char*)lB[buf];
        bfx8 a0 = *(const bfx8*)(Ab + aoff);
        bfx8 a1 = *(const bfx8*)(Ab + aoff + 1024);
        bfx8 b0 = *(const bfx8*)(Bb + boff);
        bfx8 b1 = *(const bfx8*)(Bb + boff + 1024);
        bfx8 b2 = *(const bfx8*)(Bb + boff + 2048);
        bfx8 b3 = *(const bfx8*)(Bb + boff + 3072);
        acc[0][0] = __builtin_amdgcn_mfma_f32_16x16x32_bf16(a0, b0, acc[0][0], 0, 0, 0);
        acc[0][1] = __builtin_amdgcn_mfma_f32_16x16x32_bf16(a0, b1, acc[0][1], 0, 0, 0);
        acc[0][2] = __builtin_amdgcn_mfma_f32_16x16x32_bf16(a0, b2, acc[0][2], 0, 0, 0);
        acc[0][3] = __builtin_amdgcn_mfma_f32_16x16x32_bf16(a0, b3, acc[0][3], 0, 0, 0);
        acc[1][0] = __builtin_amdgcn_mfma_f32_16x16x32_bf16(a1, b0, acc[1][0], 0, 0, 0);
        acc[1][1] = __builtin_amdgcn_mfma_f32_16x16x32_bf16(a1, b1, acc[1][1], 0, 0, 0);
        acc[1][2] = __builtin_amdgcn_mfma_f32_16x16x32_bf16(a1, b2, acc[1][2], 0, 0, 0);
        acc[1][3] = __builtin_amdgcn_mfma_f32_16x16x32_bf16(a1, b3, acc[1][3], 0, 0, 0);

        if (kc == 15) {
            int colb = tile * 128 + wn * 64 + l15;
#pragma unroll
            for (int mf = 0; mf < 2; ++mf)
#pragma unroll
                for (int j = 0; j < 4; ++j) {
                    float v0 = (colb      < NCC) ? acc[mf][0][j] + biasv[0] : -1e30f;
                    float v1 = (colb + 16 < NCC) ? acc[mf][1][j] + biasv[1] : -1e30f;
                    float v2 = (colb + 32 < NCC) ? acc[mf][2][j] + biasv[2] : -1e30f;
                    float v3 = (colb + 48 < NCC) ? acc[mf][3][j] + biasv[3] : -1e30f;
                    float cmax = fmaxf(fmaxf(v0, v1), fmaxf(v2, v3));
                    float nm = fmaxf(m_[mf][j], cmax);
                    float sacc = s_[mf][j] * __expf(m_[mf][j] - nm);
                    if (colb      < NCC) sacc += __expf(v0 - nm);
                    if (colb + 16 < NCC) sacc += __expf(v1 - nm);
                    if (colb + 32 < NCC) sacc += __expf(v2 - nm);
                    if (colb + 48 < NCC) sacc += __expf(v3 - nm);
                    s_[mf][j] = sacc;
                    m_[mf][j] = nm;
                    if (xm) {
                        if (v0 > av_[mf][j]) { av_[mf][j] = v0; ai_[mf][j] = colb; }
                        if (v1 > av_[mf][j]) { av_[mf][j] = v1; ai_[mf][j] = colb + 16; }
                        if (v2 > av_[mf][j]) { av_[mf][j] = v2; ai_[mf][j] = colb + 32; }
                        if (v3 > av_[mf][j]) { av_[mf][j] = v3; ai_[mf][j] = colb + 48; }
                    }
                    int d = tc_[mf][j] - colb;
                    if (d == 0)  tg_[mf][j] = v0;
                    if (d == 16) tg_[mf][j] = v1;
                    if (d == 32) tg_[mf][j] = v2;
                    if (d == 48) tg_[mf][j] = v3;
                }
        }
        __syncthreads();
        buf ^= 1;
    }

    // intra-wave merge across the 16-lane col group
#pragma unroll
    for (int off = 1; off < 16; off <<= 1) {
#pragma unroll
        for (int mf = 0; mf < 2; ++mf)
#pragma unroll
            for (int j = 0; j < 4; ++j) {
                float om = __shfl_xor(m_[mf][j], off);
                float os = __shfl_xor(s_[mf][j], off);
                float ot = __shfl_xor(tg_[mf][j], off);
                float ov = __shfl_xor(av_[mf][j], off);
                int   oi = __shfl_xor(ai_[mf][j], off);
                float nm = fmaxf(m_[mf][j], om);
                s_[mf][j] = s_[mf][j] * __expf(m_[mf][j] - nm) + os * __expf(om - nm);
                m_[mf][j] = nm;
                tg_[mf][j] += ot;
                if (ov > av_[mf][j] || (ov == av_[mf][j] && oi < ai_[mf][j])) {
                    av_[mf][j] = ov; ai_[mf][j] = oi;
                }
            }
    }

    // cross-wave merge (2 wn groups) via LDS (safe after final barrier)
    float* red = (float*)lB;            // m[128] s[128] tg[128] av[128] + int[128]
    int* redi = (int*)(red + 512);
    if (l15 == 0) {
#pragma unroll
        for (int mf = 0; mf < 2; ++mf)
#pragma unroll
            for (int j = 0; j < 4; ++j) {
                int rowloc = wm * 32 + mf * 16 + l4 * 4 + j;
                int idx = wn * 64 + rowloc;
                red[idx]       = m_[mf][j];
                red[128 + idx] = s_[mf][j];
                red[256 + idx] = tg_[mf][j];
                red[384 + idx] = av_[mf][j];
                redi[idx]      = ai_[mf][j];
            }
    }
    __syncthreads();
    if (t < 64) {
        int grow = row0 + t;
        if (grow < nrows) {
            float M = red[t], S = red[128 + t], T = red[256 + t];
            float V = red[384 + t]; int I = redi[t];
            float m2 = red[64 + t], s2 = red[192 + t];
            float nm = fmaxf(M, m2);
            S = S * __expf(M - nm) + s2 * __expf(m2 - nm); M = nm;
            T += red[320 + t];
            float v2 = red[448 + t]; int i2 = redi[64 + t];
            if (v2 > V || (v2 == V && i2 < I)) { V = v2; I = i2; }
            int pidx = xm ? (grow * NSL + slice) : (BB * NSL + grow * NSL + slice);
            pm[pidx] = M; ps[pidx] = S; pt[pidx] = T; pv[pidx] = V; pi[pidx] = I;
        }
    }
}

// ---------------------------------------------------------------------------
// Merge partials per row -> CE / prec1 accumulators.
// ---------------------------------------------------------------------------
__global__ void merge_kernel(const float* __restrict__ pm, const float* __restrict__ ps,
                             const float* __restrict__ pt, const float* __restrict__ pv,
                             const int* __restrict__ pi, const int* __restrict__ label,
                             float* __restrict__ sums) {
    int tid = blockIdx.x * 256 + threadIdx.x;
    float ce = 0.f, corr = 0.f;
    int isx = (tid < BB) ? 1 : 0;
    int base = -1;
    if (tid < BB) base = tid * NSL;
    else if (tid < BB + NCC) base = BB * NSL + (tid - BB) * NSL;
    if (base >= 0) {
        float M = -1e30f, S = 0.f, T = 0.f, V = -1e30f; int I = 0x7fffffff;
#pragma unroll
        for (int s2 = 0; s2 < NSL; ++s2) {
            float m = pm[base + s2], s = ps[base + s2];
            float nm = fmaxf(M, m);
            S = S * __expf(M - nm) + s * __expf(m - nm); M = nm;
            T += pt[base + s2];
            float v = pv[base + s2]; int i2 = pi[base + s2];
            if (v > V || (v == V && i2 < I)) { V = v; I = i2; }
        }
        ce = -(T - M - logf(S));
        if (isx) corr = (I == label[tid]) ? 1.f : 0.f;
    }
#pragma unroll
    for (int off = 32; off; off >>= 1) {
        ce += __shfl_xor(ce, off);
        corr += __shfl_xor(corr, off);
    }
    if ((threadIdx.x & 63) == 0) {
        atomicAdd(&sums[isx ? 0 : 2], ce);
        if (isx) atomicAdd(&sums[1], corr);
    }
}

__global__ void finalize_kernel(const float* __restrict__ sums, float* __restrict__ out) {
    out[0] = sums[0] / (float)BB + sums[2] / (float)NCC;
    out[1] = 100.0f * sums[1] / (float)BB;
}

extern "C" void kernel_launch(void* const* d_in, const int* in_sizes, int n_in,
                              void* d_out, int out_size, void* d_ws, size_t ws_size,
                              hipStream_t stream) {
    const float* x       = (const float*)d_in[0];
    const int*   label   = (const int*)d_in[1];
    const float* centers = (const float*)d_in[2];
    const float* fc_w    = (const float*)d_in[3];
    const float* fc_b    = (const float*)d_in[4];
    const float* ch_w    = (const float*)d_in[5];
    const float* ch_b    = (const float*)d_in[6];
    float* out = (float*)d_out;

    // ws layout (float offsets):
    // 0: cnti[4096] | 4096: ranki[4096] | 8192: label_add[5994] | 14186: sums[6]
    // 14192: cadd[3068928] -- consumed by newcenter, then REUSED for:
    //        14192: pm/ps/pt/pv/pi (5*121080 = 605400)
    //        619592: wbuf bf16 ch_w (1534464 float-slots)   [ends 2154056]
    // 3084144: xbuf bf16 x (1048576) | 4132720: ncbuf bf16 nc (1534464)
    float* ws = (float*)d_ws;
    int*   cnti      = (int*)ws;
    int*   ranki     = cnti + BB;
    float* label_add = ws + 2 * BB;
    float* sums      = ws + 14186;
    float* cadd      = ws + 14192;
    float* pm        = ws + 14192;
    float* ps        = pm + PSZ;
    float* pt        = ps + PSZ;
    float* pv        = pt + PSZ;
    int*   pi        = (int*)(pv + PSZ);
    unsigned short* wbuf  = (unsigned short*)(ws + 619592);
    unsigned short* xbuf  = (unsigned short*)(ws + 3084144);
    unsigned short* ncbuf = (unsigned short*)(ws + 4132720);

    hipMemsetAsync(ws, 0, 14192 * sizeof(float), stream);
    hipMemsetAsync(cadd, 0, (size_t)NCC * DD * sizeof(float), stream);

    ranks_partial<<<128, 256, 0, stream>>>(label, cnti, ranki, label_add);
    cadd_kernel<<<BB, 256, 0, stream>>>(x, label, cnti, ranki, cadd);
    newcenter_kernel<<<NCC, 256, 0, stream>>>(centers, fc_w, fc_b, cadd, label_add, ncbuf);
    // cadd consumed; overlay region now safe for partials + wbuf
    conv_both<<<((BB + NCC) * DD / 8 + 255) / 256, 256, 0, stream>>>(x, ch_w, xbuf, wbuf);

    mfma_ce_kernel<<<NBLK, 256, 0, stream>>>(xbuf, ncbuf, wbuf, ch_b, label,
                                             pm, ps, pt, pv, pi);

    merge_kernel<<<(BB + NCC + 255) / 256, 256, 0, stream>>>(pm, ps, pt, pv, pi, label, sums);
    finalize_kernel<<<1, 1, 0, stream>>>(sums, out);
}